// Round 5
// baseline (334.454 us; speedup 1.0000x reference)
//
#include <hip/hip_runtime.h>
#include <hip/hip_fp16.h>

#define BATCH 64
#define KSLOT 64
#define DDIM  128
#define HDIM  128
#define TTYPE 4
#define NSLOT (BATCH*KSLOT)
#define EPSLN 1e-5f
#define YROW  1088   // two partials: [y(512) ws(4) pad(28)] x2

typedef _Float16 v8h __attribute__((ext_vector_type(8)));
typedef float    v4f __attribute__((ext_vector_type(4)));

__device__ __forceinline__ float waveAllSum(float v) {
    #pragma unroll
    for (int m = 1; m < 64; m <<= 1) v += __shfl_xor(v, m, 64);
    return v;
}

// ---------- k_wconv: one-time weight transpose/convert to f16 [n][k] ----------
__global__ __launch_bounds__(256) void k_wconv(
        const float* __restrict__ ws1, const float* __restrict__ wi1,
        const float* __restrict__ ws2, const float* __restrict__ wu1,
        const float* __restrict__ wu2, const float* __restrict__ wi3,
        const float* __restrict__ wi2, const float* __restrict__ bi1,
        const float* __restrict__ bi3,
        __half* __restrict__ ws1T, __half* __restrict__ wi1catT,
        __half* __restrict__ ws2T, __half* __restrict__ wu1T,
        __half* __restrict__ wu2T, __half* __restrict__ w3catT,
        __half* __restrict__ w2T16, float* __restrict__ biascat) {
    __shared__ __align__(16) float tile[128*132];
    int bx = blockIdx.x, tid = threadIdx.x;
    if (bx == 21) {
        // w3catT extra cols: 512..543 and 1056..1087 = [bi3 rows | zeros]
        for (int idx = tid; idx < 128*32; idx += 256) {
            int o = idx >> 5, c = idx & 31;
            __half v = (c < 4) ? __float2half(bi3[c*DDIM + o]) : __float2half(0.f);
            w3catT[(size_t)o*YROW + 512 + c]  = v;
            w3catT[(size_t)o*YROW + 1056 + c] = v;
        }
        for (int idx = tid; idx < 1024; idx += 256) {
            int th = idx >> 7, o = idx & 127;
            biascat[idx] = (th & 1) ? bi1[(th>>1)*HDIM + o] : 0.f;
        }
        return;
    }
    const float* src; __half* dst; int dstride = 128, dcol = 0; int dup = 0;
    if (bx == 0)      { src = ws1; dst = ws1T; }
    else if (bx <= 8) { int th = bx-1, tau = th>>1, half = th&1;
                        src = wi1 + ((size_t)tau*256 + half*128)*128;
                        dst = wi1catT + (size_t)th*128*128; }
    else if (bx == 9) { src = ws2; dst = ws2T; }
    else if (bx ==10) { src = wu2; dst = wu2T; }
    else if (bx <=12) { int hh = bx-11; src = wu1 + (size_t)hh*128*128;
                        dst = wu1T; dstride = 256; dcol = hh*128; }
    else if (bx <=16) { int tau = bx-13; src = wi3 + (size_t)tau*16384;
                        dst = w3catT; dstride = YROW; dcol = tau*128; dup = 544; }
    else              { int tau = bx-17; src = wi2 + (size_t)tau*16384;
                        dst = w2T16 + (size_t)tau*16384; }
    for (int idx = tid; idx < 4096; idx += 256) {
        int r = idx >> 5, c4 = idx & 31;
        *(float4*)&tile[r*132 + c4*4] = *(const float4*)&src[(size_t)r*128 + c4*4];
    }
    __syncthreads();
    for (int idx = tid; idx < 8192; idx += 256) {
        int n = idx >> 6, kp = idx & 63;
        __half2 p = __floats2half2_rn(tile[(2*kp)*132 + n], tile[(2*kp+1)*132 + n]);
        *(__half2*)&dst[(size_t)n*dstride + dcol + 2*kp] = p;
        if (dup) *(__half2*)&dst[(size_t)n*dstride + dcol + dup + 2*kp] = p;
    }
}

// ---------- k_gemm32: AtCt = cast_f16(h) @ wi1cat + biascat ----------
__global__ __launch_bounds__(128) void k_gemm32(
        const float* __restrict__ A, const __half* __restrict__ BT,
        const float* __restrict__ bias, __half* __restrict__ outh, int K, int ostride) {
    __shared__ __align__(16) _Float16 Asm[32*40];
    __shared__ __align__(16) _Float16 Bsm[128*40];
    int tid = threadIdx.x, lane = tid & 63, w = tid >> 6;
    int n = lane & 15, quad = lane >> 4;
    int mb = blockIdx.x, nb = blockIdx.y;
    const float* Ab = A + (size_t)mb*32*K;
    const __half* Bb = BT + (size_t)nb*128*K;
    v4f acc[8];
    #pragma unroll
    for (int ot = 0; ot < 8; ot++) {
        float b0 = bias ? bias[nb*128 + ot*16 + n] : 0.f;
        acc[ot] = (v4f){b0, b0, b0, b0};
    }
    int arow = tid >> 2, aseg = (tid & 3)*8;
    for (int kk = 0; kk < K; kk += 32) {
        float4 f0 = *(const float4*)&Ab[(size_t)arow*K + kk + aseg];
        float4 f1 = *(const float4*)&Ab[(size_t)arow*K + kk + aseg + 4];
        *(__half2*)&Asm[arow*40 + aseg]     = __floats2half2_rn(f0.x, f0.y);
        *(__half2*)&Asm[arow*40 + aseg + 2] = __floats2half2_rn(f0.z, f0.w);
        *(__half2*)&Asm[arow*40 + aseg + 4] = __floats2half2_rn(f1.x, f1.y);
        *(__half2*)&Asm[arow*40 + aseg + 6] = __floats2half2_rn(f1.z, f1.w);
        #pragma unroll
        for (int ii = 0; ii < 4; ii++)
            *(v8h*)&Bsm[(ii*32 + arow)*40 + aseg] = *(const v8h*)&Bb[(size_t)(ii*32 + arow)*K + kk + aseg];
        __syncthreads();
        v8h a = *(const v8h*)&Asm[(w*16 + n)*40 + quad*8];
        #pragma unroll
        for (int ot = 0; ot < 8; ot++)
            acc[ot] = __builtin_amdgcn_mfma_f32_16x16x32_f16(
                a, *(const v8h*)&Bsm[(ot*16 + n)*40 + quad*8], acc[ot], 0, 0, 0);
        __syncthreads();
    }
    #pragma unroll
    for (int ot = 0; ot < 8; ot++)
        #pragma unroll
        for (int r = 0; r < 4; r++) {
            int row = mb*32 + w*16 + quad*4 + r, col = nb*128 + ot*16 + n;
            outh[(size_t)row*ostride + col] = __float2half(acc[ot][r]);
        }
}

// ---------- k_gemm16: comb parts = Ycat @ w3catT, split-K (kb=0/1) ----------
__global__ __launch_bounds__(256) void k_gemm16(
        const __half* __restrict__ A, const __half* __restrict__ BT,
        float* __restrict__ comb, float* __restrict__ comb2) {
    __shared__ __align__(16) _Float16 Asm[16*40];
    __shared__ __align__(16) _Float16 Bsm[128*40];
    int tid = threadIdx.x, lane = tid & 63, w = tid >> 6;
    int n = lane & 15, quad = lane >> 4;
    int mb = blockIdx.x, kb = blockIdx.y;
    const __half* Ab = A + (size_t)mb*16*YROW;
    v4f acc[2];
    acc[0] = (v4f){0.f,0.f,0.f,0.f};
    acc[1] = (v4f){0.f,0.f,0.f,0.f};
    for (int kk = kb*544; kk < kb*544 + 544; kk += 32) {
        for (int idx = tid; idx < 576; idx += 256) {
            if (idx < 64) {
                int r = idx >> 2, seg = (idx & 3)*8;
                *(v8h*)&Asm[r*40 + seg] = *(const v8h*)&Ab[(size_t)r*YROW + kk + seg];
            } else {
                int bidx = idx - 64;
                int r = bidx >> 2, seg = (bidx & 3)*8;
                *(v8h*)&Bsm[r*40 + seg] = *(const v8h*)&BT[(size_t)r*YROW + kk + seg];
            }
        }
        __syncthreads();
        v8h a = *(const v8h*)&Asm[n*40 + quad*8];
        #pragma unroll
        for (int o2 = 0; o2 < 2; o2++)
            acc[o2] = __builtin_amdgcn_mfma_f32_16x16x32_f16(
                a, *(const v8h*)&Bsm[(w*32 + o2*16 + n)*40 + quad*8], acc[o2], 0, 0, 0);
        __syncthreads();
    }
    #pragma unroll
    for (int o2 = 0; o2 < 2; o2++)
        #pragma unroll
        for (int r = 0; r < 4; r++) {
            int row = mb*16 + quad*4 + r, col = w*32 + o2*16 + n;
            if (kb == 0) comb[(size_t)row*256 + 128 + col] = acc[o2][r];
            else         comb2[(size_t)row*128 + col]      = acc[o2][r];
        }
}

// ---------- k_fused_self: LN + MLP(f_self) + residual -> comb[:,0:128] ----------
__global__ __launch_bounds__(256) void k_fused_self(
        const float* __restrict__ h, const float* __restrict__ g, const float* __restrict__ bb,
        const __half* __restrict__ ws1T, const float* __restrict__ bs1,
        const __half* __restrict__ ws2T, const float* __restrict__ bs2,
        float* __restrict__ comb) {
    __shared__ __align__(16) float    Hrow[16*132];
    __shared__ __align__(16) _Float16 Xa[16*136];
    __shared__ __align__(16) _Float16 Tt[16*136];
    int tid = threadIdx.x, lane = tid & 63, w = tid >> 6;
    int n = lane & 15, quad = lane >> 4;
    int row0 = blockIdx.x*16;
    // weight fragments straight from L2 (reused 16 rows within block)
    v8h b1[2][4], b2[2][4];
    #pragma unroll
    for (int ot = 0; ot < 2; ot++)
        #pragma unroll
        for (int ks = 0; ks < 4; ks++) {
            int col = w*32 + ot*16 + n;
            b1[ot][ks] = *(const v8h*)&ws1T[(size_t)col*128 + ks*32 + quad*8];
            b2[ot][ks] = *(const v8h*)&ws2T[(size_t)col*128 + ks*32 + quad*8];
        }
    for (int idx = tid; idx < 16*32; idx += 256) {
        int r = idx >> 5, c4 = (idx & 31)*4;
        *(float4*)&Hrow[r*132 + c4] = *(const float4*)&h[(size_t)(row0 + r)*128 + c4];
    }
    __syncthreads();
    #pragma unroll
    for (int rr = 0; rr < 4; rr++) {
        int r = w*4 + rr;
        float x0 = Hrow[r*132 + 2*lane], x1 = Hrow[r*132 + 2*lane + 1];
        float mu = waveAllSum(x0 + x1) * (1.f/128.f);
        float d0 = x0 - mu, d1 = x1 - mu;
        float var = waveAllSum(d0*d0 + d1*d1) * (1.f/128.f);
        float rs = rsqrtf(var + EPSLN);
        float2 gv = *(const float2*)&g[2*lane];
        float2 bv = *(const float2*)&bb[2*lane];
        *(__half2*)&Xa[r*136 + 2*lane] = __floats2half2_rn(d0*rs*gv.x + bv.x, d1*rs*gv.y + bv.y);
    }
    __syncthreads();
    v4f acc[2];
    #pragma unroll
    for (int ot = 0; ot < 2; ot++) { float b0 = bs1[w*32 + ot*16 + n]; acc[ot] = (v4f){b0,b0,b0,b0}; }
    #pragma unroll
    for (int ks = 0; ks < 4; ks++) {
        v8h a = *(const v8h*)&Xa[n*136 + ks*32 + quad*8];
        #pragma unroll
        for (int ot = 0; ot < 2; ot++)
            acc[ot] = __builtin_amdgcn_mfma_f32_16x16x32_f16(a, b1[ot][ks], acc[ot], 0, 0, 0);
    }
    #pragma unroll
    for (int ot = 0; ot < 2; ot++)
        #pragma unroll
        for (int r = 0; r < 4; r++)
            Tt[(quad*4 + r)*136 + w*32 + ot*16 + n] = (_Float16)fmaxf(acc[ot][r], 0.f);
    __syncthreads();
    #pragma unroll
    for (int ot = 0; ot < 2; ot++) { float b0 = bs2[w*32 + ot*16 + n]; acc[ot] = (v4f){b0,b0,b0,b0}; }
    #pragma unroll
    for (int ks = 0; ks < 4; ks++) {
        v8h a = *(const v8h*)&Tt[n*136 + ks*32 + quad*8];
        #pragma unroll
        for (int ot = 0; ot < 2; ot++)
            acc[ot] = __builtin_amdgcn_mfma_f32_16x16x32_f16(a, b2[ot][ks], acc[ot], 0, 0, 0);
    }
    #pragma unroll
    for (int ot = 0; ot < 2; ot++)
        #pragma unroll
        for (int r = 0; r < 4; r++) {
            int rr = quad*4 + r, col = w*32 + ot*16 + n;
            comb[(size_t)(row0 + rr)*256 + col] = Hrow[rr*132 + col] + acc[ot][r];
        }
}

// ---------- k_fused_update: LN(256) + MLP(update) + residual -> hout ----------
__global__ __launch_bounds__(256) void k_fused_update(
        const float* __restrict__ comb, const float* __restrict__ comb2,
        const float* __restrict__ g, const float* __restrict__ bb,
        const __half* __restrict__ wu1T, const float* __restrict__ bu1,
        const __half* __restrict__ wu2T, const float* __restrict__ bu2,
        const float* __restrict__ h, float* __restrict__ hout) {
    __shared__ __align__(16) float    Crow[16*260];
    __shared__ __align__(16) _Float16 Xa[16*264];
    __shared__ __align__(16) _Float16 Ut[16*136];
    int tid = threadIdx.x, lane = tid & 63, w = tid >> 6;
    int n = lane & 15, quad = lane >> 4;
    int row0 = blockIdx.x*16;
    v8h b1[2][8], b2[2][4];
    #pragma unroll
    for (int ot = 0; ot < 2; ot++) {
        int col = w*32 + ot*16 + n;
        #pragma unroll
        for (int ks = 0; ks < 8; ks++)
            b1[ot][ks] = *(const v8h*)&wu1T[(size_t)col*256 + ks*32 + quad*8];
        #pragma unroll
        for (int ks = 0; ks < 4; ks++)
            b2[ot][ks] = *(const v8h*)&wu2T[(size_t)col*128 + ks*32 + quad*8];
    }
    for (int idx = tid; idx < 16*64; idx += 256) {
        int r = idx >> 6, c4 = (idx & 63)*4;
        float4 v = *(const float4*)&comb[(size_t)(row0 + r)*256 + c4];
        if (c4 >= 128) {
            float4 v2 = *(const float4*)&comb2[(size_t)(row0 + r)*128 + c4 - 128];
            v.x += v2.x; v.y += v2.y; v.z += v2.z; v.w += v2.w;
        }
        *(float4*)&Crow[r*260 + c4] = v;
    }
    __syncthreads();
    #pragma unroll
    for (int rr = 0; rr < 4; rr++) {
        int r = w*4 + rr;
        float4 v = *(const float4*)&Crow[r*260 + 4*lane];
        float mu = waveAllSum(v.x + v.y + v.z + v.w) * (1.f/256.f);
        float d0 = v.x-mu, d1 = v.y-mu, d2 = v.z-mu, d3 = v.w-mu;
        float var = waveAllSum(d0*d0 + d1*d1 + d2*d2 + d3*d3) * (1.f/256.f);
        float rs = rsqrtf(var + EPSLN);
        float4 gv = *(const float4*)&g[4*lane];
        float4 bv = *(const float4*)&bb[4*lane];
        *(__half2*)&Xa[r*264 + 4*lane]     = __floats2half2_rn(d0*rs*gv.x + bv.x, d1*rs*gv.y + bv.y);
        *(__half2*)&Xa[r*264 + 4*lane + 2] = __floats2half2_rn(d2*rs*gv.z + bv.z, d3*rs*gv.w + bv.w);
    }
    __syncthreads();
    v4f acc[2];
    #pragma unroll
    for (int ot = 0; ot < 2; ot++) { float b0 = bu1[w*32 + ot*16 + n]; acc[ot] = (v4f){b0,b0,b0,b0}; }
    #pragma unroll
    for (int ks = 0; ks < 8; ks++) {
        v8h a = *(const v8h*)&Xa[n*264 + ks*32 + quad*8];
        #pragma unroll
        for (int ot = 0; ot < 2; ot++)
            acc[ot] = __builtin_amdgcn_mfma_f32_16x16x32_f16(a, b1[ot][ks], acc[ot], 0, 0, 0);
    }
    #pragma unroll
    for (int ot = 0; ot < 2; ot++)
        #pragma unroll
        for (int r = 0; r < 4; r++)
            Ut[(quad*4 + r)*136 + w*32 + ot*16 + n] = (_Float16)fmaxf(acc[ot][r], 0.f);
    __syncthreads();
    #pragma unroll
    for (int ot = 0; ot < 2; ot++) { float b0 = bu2[w*32 + ot*16 + n]; acc[ot] = (v4f){b0,b0,b0,b0}; }
    #pragma unroll
    for (int ks = 0; ks < 4; ks++) {
        v8h a = *(const v8h*)&Ut[n*136 + ks*32 + quad*8];
        #pragma unroll
        for (int ot = 0; ot < 2; ot++)
            acc[ot] = __builtin_amdgcn_mfma_f32_16x16x32_f16(a, b2[ot][ks], acc[ot], 0, 0, 0);
    }
    #pragma unroll
    for (int ot = 0; ot < 2; ot++)
        #pragma unroll
        for (int r = 0; r < 4; r++) {
            int rr = quad*4 + r, col = w*32 + ot*16 + n;
            hout[(size_t)(row0 + rr)*128 + col] = h[(size_t)(row0 + rr)*128 + col] + acc[ot][r];
        }
}

// ---------- k_pair: sender-split MFMA pair kernel, 2 blocks/CU ----------
#define LROW 136
__global__ __launch_bounds__(512, 4) void k_pair(
        const __half* __restrict__ AtCt,   // [4096][1024]
        const __half* __restrict__ w2T16,  // [4][128][128]
        const float* __restrict__ bi2,
        const float* __restrict__ ep, const float* __restrict__ et,
        __half* __restrict__ Ycat) {       // [4096][YROW]
    __shared__ __align__(16) _Float16 w2T[HDIM*LROW];   // 34816
    __shared__ __align__(16) _Float16 Cs[KSLOT*LROW];   // 17408
    __shared__ __align__(16) _Float16 As[32*LROW];      //  8704
    __shared__ __align__(16) float    wSf[32*KSLOT];    //  8192 -> 69120 B
    int bx = blockIdx.x;
    int b = bx >> 3, tau = (bx >> 1) & 3, ih = bx & 1;
    int tid = threadIdx.x, lane = tid & 63, w = tid >> 6;
    int jt = w >> 1, oh = w & 1, quad = lane >> 4, n = lane & 15;

    for (int idx = tid; idx < 2048; idx += 512) {
        int o = idx >> 4, seg = (idx & 15)*8;
        *(v8h*)&w2T[o*LROW + seg] = *(const v8h*)&w2T16[((size_t)tau*128 + o)*128 + seg];
    }
    for (int u = tid; u < 1024; u += 512) {            // Cs: all 64 receivers
        int j = u >> 4, seg = (u & 15)*8;
        *(v8h*)&Cs[j*LROW + seg] = *(const v8h*)&AtCt[(size_t)(b*KSLOT + j)*1024 + tau*256 + 128 + seg];
    }
    {                                                  // As: 32 senders (one unit per thread)
        int il = tid >> 4, seg = (tid & 15)*8;
        *(v8h*)&As[il*LROW + seg] = *(const v8h*)&AtCt[(size_t)(b*KSLOT + ih*32 + il)*1024 + tau*256 + seg];
    }
    {
        const float* epb = ep + (size_t)b*KSLOT*KSLOT + (size_t)ih*32*KSLOT;
        const float* etb = et + (size_t)b*KSLOT*KSLOT*TTYPE + (size_t)ih*32*KSLOT*TTYPE + tau;
        for (int idx = tid; idx < 32*KSLOT; idx += 512)
            wSf[idx] = epb[idx] * etb[(size_t)idx*TTYPE];
    }
    __syncthreads();

    v8h bfrag[4][4];
    #pragma unroll
    for (int ot = 0; ot < 4; ot++)
        #pragma unroll
        for (int ks = 0; ks < 4; ks++)
            bfrag[ot][ks] = *(const v8h*)&w2T[(oh*64 + ot*16 + n)*LROW + ks*32 + quad*8];
    v8h cfrag[4];
    #pragma unroll
    for (int ks = 0; ks < 4; ks++)
        cfrag[ks] = *(const v8h*)&Cs[(jt*16 + n)*LROW + ks*32 + quad*8];
    float biasv[4];
    #pragma unroll
    for (int ot = 0; ot < 4; ot++) biasv[ot] = bi2[tau*HDIM + oh*64 + ot*16 + n];

    v4f yacc[4];
    #pragma unroll
    for (int ot = 0; ot < 4; ot++) yacc[ot] = (v4f){0.f,0.f,0.f,0.f};
    float wsacc[4] = {0.f,0.f,0.f,0.f};
    const v8h zero8 = {0,0,0,0,0,0,0,0};

    for (int il = 0; il < 32; ++il) {
        v8h x1[4];
        #pragma unroll
        for (int ks = 0; ks < 4; ks++) {
            v8h a = *(const v8h*)&As[il*LROW + ks*32 + quad*8];
            x1[ks] = __builtin_elementwise_max(a + cfrag[ks], zero8);
        }
        v4f wv = *(const v4f*)&wSf[il*KSLOT + jt*16 + quad*4];
        #pragma unroll
        for (int ot = 0; ot < 4; ot++) {
            v4f acc = (v4f){biasv[ot], biasv[ot], biasv[ot], biasv[ot]};
            #pragma unroll
            for (int ks = 0; ks < 4; ks++)
                acc = __builtin_amdgcn_mfma_f32_16x16x32_f16(x1[ks], bfrag[ot][ks], acc, 0, 0, 0);
            #pragma unroll
            for (int r = 0; r < 4; r++)
                yacc[ot][r] = fmaf(wv[r], fmaxf(acc[r], 0.f), yacc[ot][r]);
        }
        #pragma unroll
        for (int r = 0; r < 4; r++) wsacc[r] += wv[r];
    }

    #pragma unroll
    for (int r = 0; r < 4; r++) {
        int j = jt*16 + quad*4 + r;
        __half* yb = Ycat + (size_t)(b*KSLOT + j)*YROW + ih*544 + tau*128 + oh*64;
        #pragma unroll
        for (int ot = 0; ot < 4; ot++)
            yb[ot*16 + n] = __float2half(yacc[ot][r]);
    }
    if (oh == 0 && n == 0) {
        #pragma unroll
        for (int r = 0; r < 4; r++)
            Ycat[(size_t)(b*KSLOT + jt*16 + quad*4 + r)*YROW + ih*544 + 512 + tau] = __float2half(wsacc[r]);
    }
}

// ---------- launch ----------
extern "C" void kernel_launch(void* const* d_in, const int* in_sizes, int n_in,
                              void* d_out, int out_size, void* d_ws, size_t ws_size,
                              hipStream_t stream) {
    const float* slots = (const float*)d_in[0];
    const float* ep    = (const float*)d_in[1];
    const float* et    = (const float*)d_in[2];
    const float* ls_g  = (const float*)d_in[3];
    const float* ls_b  = (const float*)d_in[4];
    const float* ws1   = (const float*)d_in[5];
    const float* bs1   = (const float*)d_in[6];
    const float* ws2   = (const float*)d_in[7];
    const float* bs2   = (const float*)d_in[8];
    const float* wi1   = (const float*)d_in[9];
    const float* bi1   = (const float*)d_in[10];
    const float* wi2   = (const float*)d_in[11];
    const float* bi2   = (const float*)d_in[12];
    const float* wi3   = (const float*)d_in[13];
    const float* bi3   = (const float*)d_in[14];
    const float* lu_g  = (const float*)d_in[15];
    const float* lu_b  = (const float*)d_in[16];
    const float* wu1   = (const float*)d_in[17];
    const float* bu1   = (const float*)d_in[18];
    const float* wu2   = (const float*)d_in[19];
    const float* bu2   = (const float*)d_in[20];
    float* out = (float*)d_out;

    char* p = (char*)d_ws;
    float*  h_buf   = (float*)p;   p += (size_t)NSLOT*DDIM*4;
    __half* AtCt    = (__half*)p;  p += (size_t)NSLOT*1024*2;
    __half* Ycat    = (__half*)p;  p += (size_t)NSLOT*YROW*2;
    float*  comb    = (float*)p;   p += (size_t)NSLOT*256*4;
    float*  comb2   = (float*)p;   p += (size_t)NSLOT*128*4;
    __half* ws1T    = (__half*)p;  p += 128*128*2;
    __half* wi1catT = (__half*)p;  p += 1024*128*2;
    __half* ws2T    = (__half*)p;  p += 128*128*2;
    __half* wu1T    = (__half*)p;  p += 128*256*2;
    __half* wu2T    = (__half*)p;  p += 128*128*2;
    __half* w3catT  = (__half*)p;  p += 128*YROW*2;
    __half* w2T16   = (__half*)p;  p += 4*128*128*2;
    float*  biascat = (float*)p;   p += 1024*4;

    k_wconv<<<22, 256, 0, stream>>>(ws1, wi1, ws2, wu1, wu2, wi3, wi2, bi1, bi3,
                                    ws1T, wi1catT, ws2T, wu1T, wu2T, w3catT, w2T16, biascat);

    for (int mp = 0; mp < 2; mp++) {
        const float* h = (mp == 0) ? slots : h_buf;
        float* hout = (mp == 0) ? h_buf : out;
        k_gemm32<<<dim3(128, 8), 128, 0, stream>>>(h, wi1catT, biascat, AtCt, 128, 1024);
        k_fused_self<<<NSLOT/16, 256, 0, stream>>>(h, ls_g, ls_b, ws1T, bs1, ws2T, bs2, comb);
        k_pair<<<BATCH*TTYPE*2, 512, 0, stream>>>(AtCt, w2T16, bi2, ep, et, Ycat);
        k_gemm16<<<dim3(256, 2), 256, 0, stream>>>(Ycat, w3catT, comb, comb2);
        k_fused_update<<<NSLOT/16, 256, 0, stream>>>(comb, comb2, lu_g, lu_b, wu1T, bu1,
                                                     wu2T, bu2, h, hout);
    }
}

// Round 6
// 229.301 us; speedup vs baseline: 1.4586x; 1.4586x over previous
//
#include <hip/hip_runtime.h>
#include <hip/hip_fp16.h>

#define BATCH 64
#define KSLOT 64
#define DDIM  128
#define HDIM  128
#define TTYPE 4
#define NSLOT (BATCH*KSLOT)
#define EPSLN 1e-5f
#define YROW  544   // 4*128 y + 4 wsum + 28 pad (pad killed by zero weight cols)

typedef _Float16 v8h __attribute__((ext_vector_type(8)));
typedef float    v4f __attribute__((ext_vector_type(4)));

__device__ __forceinline__ float waveAllSum(float v) {
    #pragma unroll
    for (int m = 1; m < 64; m <<= 1) v += __shfl_xor(v, m, 64);
    return v;
}

// ---------- k_wconv: one-time weight transpose/convert to f16 [n][k] ----------
__global__ __launch_bounds__(256) void k_wconv(
        const float* __restrict__ ws1, const float* __restrict__ wi1,
        const float* __restrict__ ws2, const float* __restrict__ wu1,
        const float* __restrict__ wu2, const float* __restrict__ wi3,
        const float* __restrict__ wi2, const float* __restrict__ bi1,
        const float* __restrict__ bi3,
        __half* __restrict__ ws1T, __half* __restrict__ wi1catT,
        __half* __restrict__ ws2T, __half* __restrict__ wu1T,
        __half* __restrict__ wu2T, __half* __restrict__ w3catT,
        __half* __restrict__ w2T16, float* __restrict__ biascat) {
    __shared__ __align__(16) float tile[128*132];
    int bx = blockIdx.x, tid = threadIdx.x;
    if (bx == 21) {
        // w3catT cols 512..543 = [bi3 rows | zeros]; biascat
        for (int idx = tid; idx < 128*32; idx += 256) {
            int o = idx >> 5, c = idx & 31;
            w3catT[(size_t)o*YROW + 512 + c] = (c < 4) ? __float2half(bi3[c*DDIM + o]) : __float2half(0.f);
        }
        for (int idx = tid; idx < 1024; idx += 256) {
            int th = idx >> 7, o = idx & 127;
            biascat[idx] = (th & 1) ? bi1[(th>>1)*HDIM + o] : 0.f;
        }
        return;
    }
    const float* src; __half* dst; int dstride = 128, dcol = 0;
    if (bx == 0)      { src = ws1; dst = ws1T; }
    else if (bx <= 8) { int th = bx-1, tau = th>>1, half = th&1;
                        src = wi1 + ((size_t)tau*256 + half*128)*128;
                        dst = wi1catT + (size_t)th*128*128; }
    else if (bx == 9) { src = ws2; dst = ws2T; }
    else if (bx ==10) { src = wu2; dst = wu2T; }
    else if (bx <=12) { int hh = bx-11; src = wu1 + (size_t)hh*128*128;
                        dst = wu1T; dstride = 256; dcol = hh*128; }
    else if (bx <=16) { int tau = bx-13; src = wi3 + (size_t)tau*16384;
                        dst = w3catT; dstride = YROW; dcol = tau*128; }
    else              { int tau = bx-17; src = wi2 + (size_t)tau*16384;
                        dst = w2T16 + (size_t)tau*16384; }
    for (int idx = tid; idx < 4096; idx += 256) {
        int r = idx >> 5, c4 = idx & 31;
        *(float4*)&tile[r*132 + c4*4] = *(const float4*)&src[(size_t)r*128 + c4*4];
    }
    __syncthreads();
    for (int idx = tid; idx < 8192; idx += 256) {
        int n = idx >> 6, kp = idx & 63;
        __half2 p = __floats2half2_rn(tile[(2*kp)*132 + n], tile[(2*kp+1)*132 + n]);
        *(__half2*)&dst[(size_t)n*dstride + dcol + 2*kp] = p;
    }
}

// ---------- k_front: nb<4 -> AtCt 16x256 tile; nb==4 -> f_self chain -> comb128 ----------
__global__ __launch_bounds__(256) void k_front(
        const float* __restrict__ h,
        const __half* __restrict__ wi1catT, const float* __restrict__ biascat,
        const float* __restrict__ ls_g, const float* __restrict__ ls_b,
        const __half* __restrict__ ws1T, const float* __restrict__ bs1,
        const __half* __restrict__ ws2T, const float* __restrict__ bs2,
        __half* __restrict__ AtCt, float* __restrict__ comb128) {
    __shared__ __align__(16) char smem[17152];
    int tid = threadIdx.x, lane = tid & 63, w = tid >> 6;
    int n = lane & 15, quad = lane >> 4;
    int row0 = blockIdx.x*16, nb = blockIdx.y;
    if (nb < 4) {
        _Float16* Ha = (_Float16*)smem;             // [16][136]
        for (int u = tid; u < 16*32; u += 256) {
            int r = u >> 5, c4 = (u & 31)*4;
            float4 f = *(const float4*)&h[(size_t)(row0 + r)*128 + c4];
            *(__half2*)&Ha[r*136 + c4]     = __floats2half2_rn(f.x, f.y);
            *(__half2*)&Ha[r*136 + c4 + 2] = __floats2half2_rn(f.z, f.w);
        }
        __syncthreads();
        v8h bfrag[4][4];
        #pragma unroll
        for (int ot = 0; ot < 4; ot++) {
            int col = nb*256 + w*64 + ot*16 + n;
            #pragma unroll
            for (int ks = 0; ks < 4; ks++)
                bfrag[ot][ks] = *(const v8h*)&wi1catT[(size_t)col*128 + ks*32 + quad*8];
        }
        v4f acc[4];
        #pragma unroll
        for (int ot = 0; ot < 4; ot++) {
            float b0 = biascat[nb*256 + w*64 + ot*16 + n];
            acc[ot] = (v4f){b0, b0, b0, b0};
        }
        #pragma unroll
        for (int ks = 0; ks < 4; ks++) {
            v8h a = *(const v8h*)&Ha[n*136 + ks*32 + quad*8];
            #pragma unroll
            for (int ot = 0; ot < 4; ot++)
                acc[ot] = __builtin_amdgcn_mfma_f32_16x16x32_f16(a, bfrag[ot][ks], acc[ot], 0, 0, 0);
        }
        #pragma unroll
        for (int ot = 0; ot < 4; ot++)
            #pragma unroll
            for (int r = 0; r < 4; r++) {
                int row = row0 + quad*4 + r, col = nb*256 + w*64 + ot*16 + n;
                AtCt[(size_t)row*1024 + col] = __float2half(acc[ot][r]);
            }
    } else {
        float*    Hrow = (float*)smem;              // [16][132]
        _Float16* Xa = (_Float16*)(smem + 8448);    // [16][136]
        _Float16* Tt = (_Float16*)(smem + 8448 + 4352);
        v8h b1[2][4], b2[2][4];
        #pragma unroll
        for (int ot = 0; ot < 2; ot++) {
            int col = w*32 + ot*16 + n;
            #pragma unroll
            for (int ks = 0; ks < 4; ks++) {
                b1[ot][ks] = *(const v8h*)&ws1T[(size_t)col*128 + ks*32 + quad*8];
                b2[ot][ks] = *(const v8h*)&ws2T[(size_t)col*128 + ks*32 + quad*8];
            }
        }
        for (int u = tid; u < 16*32; u += 256) {
            int r = u >> 5, c4 = (u & 31)*4;
            *(float4*)&Hrow[r*132 + c4] = *(const float4*)&h[(size_t)(row0 + r)*128 + c4];
        }
        __syncthreads();
        #pragma unroll
        for (int rr = 0; rr < 4; rr++) {
            int r = w*4 + rr;
            float x0 = Hrow[r*132 + 2*lane], x1 = Hrow[r*132 + 2*lane + 1];
            float mu = waveAllSum(x0 + x1) * (1.f/128.f);
            float d0 = x0 - mu, d1 = x1 - mu;
            float var = waveAllSum(d0*d0 + d1*d1) * (1.f/128.f);
            float rs = rsqrtf(var + EPSLN);
            float2 gv = *(const float2*)&ls_g[2*lane];
            float2 bv = *(const float2*)&ls_b[2*lane];
            *(__half2*)&Xa[r*136 + 2*lane] = __floats2half2_rn(d0*rs*gv.x + bv.x, d1*rs*gv.y + bv.y);
        }
        __syncthreads();
        v4f acc[2];
        #pragma unroll
        for (int ot = 0; ot < 2; ot++) { float b0 = bs1[w*32 + ot*16 + n]; acc[ot] = (v4f){b0,b0,b0,b0}; }
        #pragma unroll
        for (int ks = 0; ks < 4; ks++) {
            v8h a = *(const v8h*)&Xa[n*136 + ks*32 + quad*8];
            #pragma unroll
            for (int ot = 0; ot < 2; ot++)
                acc[ot] = __builtin_amdgcn_mfma_f32_16x16x32_f16(a, b1[ot][ks], acc[ot], 0, 0, 0);
        }
        #pragma unroll
        for (int ot = 0; ot < 2; ot++)
            #pragma unroll
            for (int r = 0; r < 4; r++)
                Tt[(quad*4 + r)*136 + w*32 + ot*16 + n] = (_Float16)fmaxf(acc[ot][r], 0.f);
        __syncthreads();
        #pragma unroll
        for (int ot = 0; ot < 2; ot++) { float b0 = bs2[w*32 + ot*16 + n]; acc[ot] = (v4f){b0,b0,b0,b0}; }
        #pragma unroll
        for (int ks = 0; ks < 4; ks++) {
            v8h a = *(const v8h*)&Tt[n*136 + ks*32 + quad*8];
            #pragma unroll
            for (int ot = 0; ot < 2; ot++)
                acc[ot] = __builtin_amdgcn_mfma_f32_16x16x32_f16(a, b2[ot][ks], acc[ot], 0, 0, 0);
        }
        #pragma unroll
        for (int ot = 0; ot < 2; ot++)
            #pragma unroll
            for (int r = 0; r < 4; r++) {
                int rr = quad*4 + r, col = w*32 + ot*16 + n;
                comb128[(size_t)(row0 + rr)*128 + col] = Hrow[rr*132 + col] + acc[ot][r];
            }
    }
}

// ---------- k_pair: R4 proven version (256 blocks, 512 thr) ----------
#define LROW 136
__global__ __launch_bounds__(512) void k_pair(
        const __half* __restrict__ AtCt,   // [4096][1024]
        const __half* __restrict__ w2T16,  // [4][128][128]
        const float* __restrict__ bi2,
        const float* __restrict__ ep, const float* __restrict__ et,
        __half* __restrict__ Ycat) {       // [4096][YROW]
    __shared__ __align__(16) _Float16 w2T[HDIM*LROW];
    __shared__ __align__(16) _Float16 Cs[KSLOT*LROW];
    __shared__ __align__(16) _Float16 As[KSLOT*LROW];
    __shared__ __align__(16) _Float16 wS[KSLOT*KSLOT];
    int bx = blockIdx.x, b = bx >> 2, tau = bx & 3;
    int tid = threadIdx.x, lane = tid & 63, w = tid >> 6;
    int jt = w >> 1, oh = w & 1, quad = lane >> 4, n = lane & 15;

    for (int idx = tid; idx < 2048; idx += 512) {
        int o = idx >> 4, seg = (idx & 15)*8;
        *(v8h*)&w2T[o*LROW + seg] = *(const v8h*)&w2T16[((size_t)tau*128 + o)*128 + seg];
    }
    for (int u = tid; u < 1024; u += 512) {
        int j = u >> 4, seg = (u & 15)*8;
        const __half* rp = AtCt + (size_t)(b*KSLOT + j)*1024 + tau*256 + seg;
        *(v8h*)&As[j*LROW + seg] = *(const v8h*)&rp[0];
        *(v8h*)&Cs[j*LROW + seg] = *(const v8h*)&rp[128];
    }
    {
        const float* epb = ep + (size_t)b*KSLOT*KSLOT;
        const float* etb = et + (size_t)b*KSLOT*KSLOT*TTYPE + tau;
        for (int idx = tid; idx < KSLOT*KSLOT; idx += 512)
            wS[idx] = (_Float16)(epb[idx] * etb[(size_t)idx*TTYPE]);
    }
    __syncthreads();

    v8h bfrag[4][4];
    #pragma unroll
    for (int ot = 0; ot < 4; ot++)
        #pragma unroll
        for (int ks = 0; ks < 4; ks++)
            bfrag[ot][ks] = *(const v8h*)&w2T[(oh*64 + ot*16 + n)*LROW + ks*32 + quad*8];
    v8h cfrag[4];
    #pragma unroll
    for (int ks = 0; ks < 4; ks++)
        cfrag[ks] = *(const v8h*)&Cs[(jt*16 + n)*LROW + ks*32 + quad*8];
    float biasv[4];
    #pragma unroll
    for (int ot = 0; ot < 4; ot++) biasv[ot] = bi2[tau*HDIM + oh*64 + ot*16 + n];

    v4f yacc[4];
    #pragma unroll
    for (int ot = 0; ot < 4; ot++) yacc[ot] = (v4f){0.f,0.f,0.f,0.f};
    float wsacc[4] = {0.f,0.f,0.f,0.f};
    const v8h zero8 = {0,0,0,0,0,0,0,0};

    for (int i = 0; i < KSLOT; ++i) {
        v8h x1[4];
        #pragma unroll
        for (int ks = 0; ks < 4; ks++) {
            v8h a = *(const v8h*)&As[i*LROW + ks*32 + quad*8];
            x1[ks] = __builtin_elementwise_max(a + cfrag[ks], zero8);
        }
        _Float16 wv16[4];
        #pragma unroll
        for (int r = 0; r < 4; r++) wv16[r] = wS[i*KSLOT + jt*16 + quad*4 + r];
        #pragma unroll
        for (int ot = 0; ot < 4; ot++) {
            v4f acc = (v4f){biasv[ot], biasv[ot], biasv[ot], biasv[ot]};
            #pragma unroll
            for (int ks = 0; ks < 4; ks++)
                acc = __builtin_amdgcn_mfma_f32_16x16x32_f16(x1[ks], bfrag[ot][ks], acc, 0, 0, 0);
            #pragma unroll
            for (int r = 0; r < 4; r++)
                yacc[ot][r] = fmaf((float)wv16[r], fmaxf(acc[r], 0.f), yacc[ot][r]);
        }
        #pragma unroll
        for (int r = 0; r < 4; r++) wsacc[r] += (float)wv16[r];
    }

    #pragma unroll
    for (int r = 0; r < 4; r++) {
        int j = jt*16 + quad*4 + r;
        __half* yb = Ycat + (size_t)(b*KSLOT + j)*YROW + tau*128 + oh*64;
        #pragma unroll
        for (int ot = 0; ot < 4; ot++)
            yb[ot*16 + n] = __float2half(yacc[ot][r]);
    }
    if (oh == 0 && n == 0) {
        #pragma unroll
        for (int r = 0; r < 4; r++)
            Ycat[(size_t)(b*KSLOT + jt*16 + quad*4 + r)*YROW + 512 + tau] = __float2half(wsacc[r]);
    }
}

// ---------- k_mega: dinter GEMM (K=544) + LN(256) + update MLP + residual ----------
__global__ __launch_bounds__(256) void k_mega(
        const __half* __restrict__ Ycat, const __half* __restrict__ w3catT,
        const float* __restrict__ comb128,
        const float* __restrict__ g, const float* __restrict__ bb,
        const __half* __restrict__ wu1T, const float* __restrict__ bu1,
        const __half* __restrict__ wu2T, const float* __restrict__ bu2,
        const float* __restrict__ h, float* __restrict__ hout) {
    __shared__ __align__(16) _Float16 Ys[16*552];    // 17664
    __shared__ __align__(16) float    Crow[16*260];  // 16640
    __shared__ __align__(16) _Float16 Xa[16*264];    //  8448
    __shared__ __align__(16) _Float16 Ut[16*136];    //  4352
    int tid = threadIdx.x, lane = tid & 63, w = tid >> 6;
    int n = lane & 15, quad = lane >> 4;
    int row0 = blockIdx.x*16;
    // stage Ycat rows (544 halves) + comb cols 0..127
    for (int u = tid; u < 1024; u += 256) {
        int r = u >> 6, seg = (u & 63)*8;
        *(v8h*)&Ys[r*552 + seg] = *(const v8h*)&Ycat[(size_t)(row0 + r)*YROW + seg];
    }
    {
        int r = tid >> 2, seg = 512 + (tid & 3)*8;
        if (tid < 64) *(v8h*)&Ys[r*552 + seg] = *(const v8h*)&Ycat[(size_t)(row0 + r)*YROW + seg];
    }
    for (int u = tid; u < 16*32; u += 256) {
        int r = u >> 5, c4 = (u & 31)*4;
        *(float4*)&Crow[r*260 + c4] = *(const float4*)&comb128[(size_t)(row0 + r)*128 + c4];
    }
    __syncthreads();
    // phase 1: dinter = Ys @ w3catT^T  (16 x 128, K=544)
    {
        v4f acc[2];
        acc[0] = (v4f){0.f,0.f,0.f,0.f};
        acc[1] = (v4f){0.f,0.f,0.f,0.f};
        #pragma unroll
        for (int ks = 0; ks < 17; ks++) {
            v8h a = *(const v8h*)&Ys[n*552 + ks*32 + quad*8];
            #pragma unroll
            for (int o2 = 0; o2 < 2; o2++) {
                v8h bfr = *(const v8h*)&w3catT[(size_t)(w*32 + o2*16 + n)*YROW + ks*32 + quad*8];
                acc[o2] = __builtin_amdgcn_mfma_f32_16x16x32_f16(a, bfr, acc[o2], 0, 0, 0);
            }
        }
        #pragma unroll
        for (int o2 = 0; o2 < 2; o2++)
            #pragma unroll
            for (int r = 0; r < 4; r++)
                Crow[(quad*4 + r)*260 + 128 + w*32 + o2*16 + n] = acc[o2][r];
    }
    __syncthreads();
    // LN(256)
    #pragma unroll
    for (int rr = 0; rr < 4; rr++) {
        int r = w*4 + rr;
        float4 v = *(const float4*)&Crow[r*260 + 4*lane];
        float mu = waveAllSum(v.x + v.y + v.z + v.w) * (1.f/256.f);
        float d0 = v.x-mu, d1 = v.y-mu, d2 = v.z-mu, d3 = v.w-mu;
        float var = waveAllSum(d0*d0 + d1*d1 + d2*d2 + d3*d3) * (1.f/256.f);
        float rs = rsqrtf(var + EPSLN);
        float4 gv = *(const float4*)&g[4*lane];
        float4 bv = *(const float4*)&bb[4*lane];
        *(__half2*)&Xa[r*264 + 4*lane]     = __floats2half2_rn(d0*rs*gv.x + bv.x, d1*rs*gv.y + bv.y);
        *(__half2*)&Xa[r*264 + 4*lane + 2] = __floats2half2_rn(d2*rs*gv.z + bv.z, d3*rs*gv.w + bv.w);
    }
    __syncthreads();
    // update MLP
    v4f acc[2];
    #pragma unroll
    for (int ot = 0; ot < 2; ot++) { float b0 = bu1[w*32 + ot*16 + n]; acc[ot] = (v4f){b0,b0,b0,b0}; }
    #pragma unroll
    for (int ks = 0; ks < 8; ks++) {
        v8h a = *(const v8h*)&Xa[n*264 + ks*32 + quad*8];
        #pragma unroll
        for (int ot = 0; ot < 2; ot++) {
            v8h bfr = *(const v8h*)&wu1T[(size_t)(w*32 + ot*16 + n)*256 + ks*32 + quad*8];
            acc[ot] = __builtin_amdgcn_mfma_f32_16x16x32_f16(a, bfr, acc[ot], 0, 0, 0);
        }
    }
    #pragma unroll
    for (int ot = 0; ot < 2; ot++)
        #pragma unroll
        for (int r = 0; r < 4; r++)
            Ut[(quad*4 + r)*136 + w*32 + ot*16 + n] = (_Float16)fmaxf(acc[ot][r], 0.f);
    __syncthreads();
    #pragma unroll
    for (int ot = 0; ot < 2; ot++) { float b0 = bu2[w*32 + ot*16 + n]; acc[ot] = (v4f){b0,b0,b0,b0}; }
    #pragma unroll
    for (int ks = 0; ks < 4; ks++) {
        v8h a = *(const v8h*)&Ut[n*136 + ks*32 + quad*8];
        #pragma unroll
        for (int ot = 0; ot < 2; ot++) {
            v8h bfr = *(const v8h*)&wu2T[(size_t)(w*32 + ot*16 + n)*128 + ks*32 + quad*8];
            acc[ot] = __builtin_amdgcn_mfma_f32_16x16x32_f16(a, bfr, acc[ot], 0, 0, 0);
        }
    }
    #pragma unroll
    for (int ot = 0; ot < 2; ot++)
        #pragma unroll
        for (int r = 0; r < 4; r++) {
            int rr = quad*4 + r, col = w*32 + ot*16 + n;
            hout[(size_t)(row0 + rr)*128 + col] = h[(size_t)(row0 + rr)*128 + col] + acc[ot][r];
        }
}

// ---------- launch ----------
extern "C" void kernel_launch(void* const* d_in, const int* in_sizes, int n_in,
                              void* d_out, int out_size, void* d_ws, size_t ws_size,
                              hipStream_t stream) {
    const float* slots = (const float*)d_in[0];
    const float* ep    = (const float*)d_in[1];
    const float* et    = (const float*)d_in[2];
    const float* ls_g  = (const float*)d_in[3];
    const float* ls_b  = (const float*)d_in[4];
    const float* ws1   = (const float*)d_in[5];
    const float* bs1   = (const float*)d_in[6];
    const float* ws2   = (const float*)d_in[7];
    const float* bs2   = (const float*)d_in[8];
    const float* wi1   = (const float*)d_in[9];
    const float* bi1   = (const float*)d_in[10];
    const float* wi2   = (const float*)d_in[11];
    const float* bi2   = (const float*)d_in[12];
    const float* wi3   = (const float*)d_in[13];
    const float* bi3   = (const float*)d_in[14];
    const float* lu_g  = (const float*)d_in[15];
    const float* lu_b  = (const float*)d_in[16];
    const float* wu1   = (const float*)d_in[17];
    const float* bu1   = (const float*)d_in[18];
    const float* wu2   = (const float*)d_in[19];
    const float* bu2   = (const float*)d_in[20];
    float* out = (float*)d_out;

    char* p = (char*)d_ws;
    float*  h_buf   = (float*)p;   p += (size_t)NSLOT*DDIM*4;
    __half* AtCt    = (__half*)p;  p += (size_t)NSLOT*1024*2;
    __half* Ycat    = (__half*)p;  p += (size_t)NSLOT*YROW*2;
    float*  comb128 = (float*)p;   p += (size_t)NSLOT*128*4;
    __half* ws1T    = (__half*)p;  p += 128*128*2;
    __half* wi1catT = (__half*)p;  p += 1024*128*2;
    __half* ws2T    = (__half*)p;  p += 128*128*2;
    __half* wu1T    = (__half*)p;  p += 128*256*2;
    __half* wu2T    = (__half*)p;  p += 128*128*2;
    __half* w3catT  = (__half*)p;  p += 128*YROW*2;
    __half* w2T16   = (__half*)p;  p += 4*128*128*2;
    float*  biascat = (float*)p;   p += 1024*4;

    k_wconv<<<22, 256, 0, stream>>>(ws1, wi1, ws2, wu1, wu2, wi3, wi2, bi1, bi3,
                                    ws1T, wi1catT, ws2T, wu1T, wu2T, w3catT, w2T16, biascat);

    for (int mp = 0; mp < 2; mp++) {
        const float* h = (mp == 0) ? slots : h_buf;
        float* hout = (mp == 0) ? h_buf : out;
        k_front<<<dim3(256, 5), 256, 0, stream>>>(h, wi1catT, biascat, ls_g, ls_b,
                                                  ws1T, bs1, ws2T, bs2, AtCt, comb128);
        k_pair<<<BATCH*TTYPE, 512, 0, stream>>>(AtCt, w2T16, bi2, ep, et, Ycat);
        k_mega<<<NSLOT/16, 256, 0, stream>>>(Ycat, w3catT, comb128, lu_g, lu_b,
                                             wu1T, bu1, wu2T, bu2, h, hout);
    }
}